// Round 1
// baseline (3255.898 us; speedup 1.0000x reference)
//
#include <hip/hip_runtime.h>
#include <math.h>

#define N_TOK   16384
#define D_IN    1024
#define D_MODEL 1024
#define HID     256
#define NEXP    10
#define D_OUT   1024

// SGEMM tiling: 128x128 tile, BK=8, 256 threads, 8x8 micro-tile per thread.
#define BM 128
#define BN 128
#define BK 8

// Expert routing: pad each expert's assignment list to a multiple of EPAD so
// every 128-row tile is single-expert. Static capacity => static grid (graph-safe).
#define EPAD 128
#define A_CAP (2*N_TOK + NEXP*EPAD)   // 34048 = 266 * 128

// ---------------------------------------------------------------------------
// Dense fp32 GEMM with bias: C[M,N] = A[M,K] @ B[K,N] + bias[N]
// M,N divisible by 128; K divisible by 8.
// ---------------------------------------------------------------------------
__global__ __launch_bounds__(256)
void sgemm_bias_kernel(const float* __restrict__ A, const float* __restrict__ B,
                       const float* __restrict__ bias, float* __restrict__ C,
                       int K, int N)
{
    __shared__ float As[BK][BM + 4];
    __shared__ float Bs[BK][BN + 4];
    const int tid  = threadIdx.x;
    const int tx   = tid & 15;
    const int ty   = tid >> 4;
    const int row0 = blockIdx.y * BM;
    const int col0 = blockIdx.x * BN;

    float acc[8][8];
#pragma unroll
    for (int i = 0; i < 8; ++i)
#pragma unroll
        for (int j = 0; j < 8; ++j) acc[i][j] = 0.f;

    for (int k0 = 0; k0 < K; k0 += BK) {
#pragma unroll
        for (int i = 0; i < 4; ++i) {
            int idx = tid + i * 256;
            int r = idx >> 3, c = idx & 7;
            As[c][r] = A[(size_t)(row0 + r) * K + k0 + c];
        }
#pragma unroll
        for (int i = 0; i < 4; ++i) {
            int idx = tid + i * 256;
            int r = idx >> 7, c = idx & 127;
            Bs[r][c] = B[(size_t)(k0 + r) * N + col0 + c];
        }
        __syncthreads();
#pragma unroll
        for (int k = 0; k < BK; ++k) {
            float af[8], bf[8];
#pragma unroll
            for (int i = 0; i < 8; ++i) af[i] = As[k][ty * 8 + i];
#pragma unroll
            for (int j = 0; j < 8; ++j) bf[j] = Bs[k][tx * 8 + j];
#pragma unroll
            for (int i = 0; i < 8; ++i)
#pragma unroll
                for (int j = 0; j < 8; ++j) acc[i][j] += af[i] * bf[j];
        }
        __syncthreads();
    }

#pragma unroll
    for (int i = 0; i < 8; ++i) {
        int r = row0 + ty * 8 + i;
#pragma unroll
        for (int j = 0; j < 8; ++j) {
            int c = col0 + tx * 8 + j;
            C[(size_t)r * N + c] = acc[i][j] + bias[c];
        }
    }
}

// ---------------------------------------------------------------------------
// Routing init: zero counts/cursors, fill assignment slots with -1 (padding).
// ---------------------------------------------------------------------------
__global__ __launch_bounds__(256)
void init_kernel(int* __restrict__ counts, int* __restrict__ cursors,
                 int* __restrict__ assign_token)
{
    int i = blockIdx.x * 256 + threadIdx.x;
    if (i < NEXP) { counts[i] = 0; cursors[i] = 0; }
    if (i < A_CAP) assign_token[i] = -1;
}

// ---------------------------------------------------------------------------
// Gate: logits = a @ Wg + bg (fp32, 1 wave per token), top-2 (lowest-index
// tie-break like lax.top_k), normalized weights from logits directly.
// ---------------------------------------------------------------------------
__global__ __launch_bounds__(256)
void gate_kernel(const float* __restrict__ a, const float* __restrict__ Wg,
                 const float* __restrict__ bg,
                 int* __restrict__ route_e, float* __restrict__ route_w,
                 int* __restrict__ counts)
{
    const int wave = threadIdx.x >> 6;
    const int lane = threadIdx.x & 63;
    const int n = blockIdx.x * 4 + wave;

    float p[NEXP];
#pragma unroll
    for (int e = 0; e < NEXP; ++e) p[e] = 0.f;

    const float* arow = a + (size_t)n * D_MODEL;
    for (int d = lane; d < D_MODEL; d += 64) {
        float av = arow[d];
        const float* wgr = Wg + (size_t)d * NEXP;
#pragma unroll
        for (int e = 0; e < NEXP; ++e) p[e] += av * wgr[e];
    }
#pragma unroll
    for (int e = 0; e < NEXP; ++e) {
        float v = p[e];
        for (int off = 32; off > 0; off >>= 1) v += __shfl_down(v, off);
        p[e] = v;
    }
    if (lane == 0) {
        float lg[NEXP];
#pragma unroll
        for (int e = 0; e < NEXP; ++e) lg[e] = p[e] + bg[e];
        int e0 = 0; float v0 = lg[0];
        for (int e = 1; e < NEXP; ++e) if (lg[e] > v0) { v0 = lg[e]; e0 = e; }
        int e1 = -1; float v1 = -3.0e38f;
        for (int e = 0; e < NEXP; ++e) {
            if (e == e0) continue;
            if (lg[e] > v1) { v1 = lg[e]; e1 = e; }
        }
        // softmax + top-2 renorm == 1/(1+exp(l1-l0))
        float w0 = 1.f / (1.f + expf(v1 - v0));
        float w1 = 1.f - w0;
        route_e[n * 2]     = e0;
        route_e[n * 2 + 1] = e1;
        route_w[n * 2]     = w0;
        route_w[n * 2 + 1] = w1;
        atomicAdd(&counts[e0], 1);
        atomicAdd(&counts[e1], 1);
    }
}

// ---------------------------------------------------------------------------
// Aligned (EPAD) exclusive prefix of counts -> offs[NEXP+1].
// ---------------------------------------------------------------------------
__global__ void offsets_kernel(const int* __restrict__ counts, int* __restrict__ offs)
{
    if (threadIdx.x == 0 && blockIdx.x == 0) {
        int acc = 0;
        for (int e = 0; e < NEXP; ++e) {
            offs[e] = acc;
            acc += (counts[e] + EPAD - 1) / EPAD * EPAD;
        }
        offs[NEXP] = acc;
    }
}

// ---------------------------------------------------------------------------
// Scatter assignments into expert-grouped (padded) lists.
// ---------------------------------------------------------------------------
__global__ __launch_bounds__(256)
void scatter_kernel(const int* __restrict__ route_e, const float* __restrict__ route_w,
                    const int* __restrict__ offs, int* __restrict__ cursors,
                    int* __restrict__ assign_token, float* __restrict__ assign_w)
{
    int i = blockIdx.x * 256 + threadIdx.x;
    if (i >= 2 * N_TOK) return;
    int e = route_e[i];
    int pos = atomicAdd(&cursors[e], 1);
    int slot = offs[e] + pos;
    assign_token[slot] = i >> 1;
    assign_w[slot] = route_w[i];
}

// ---------------------------------------------------------------------------
// out[n][c] = w0*b2[e0][c] + w1*b2[e1][c]   (combine @ b2), float4 stores.
// ---------------------------------------------------------------------------
__global__ __launch_bounds__(256)
void out_init_kernel(const int* __restrict__ route_e, const float* __restrict__ route_w,
                     const float* __restrict__ b2, float* __restrict__ out)
{
    int id4 = blockIdx.x * 256 + threadIdx.x;
    int base = id4 * 4;
    int n = base >> 10;
    int c = base & 1023;
    int e0 = route_e[n * 2], e1 = route_e[n * 2 + 1];
    float w0 = route_w[n * 2], w1 = route_w[n * 2 + 1];
    const float4 b0 = *(const float4*)(b2 + (size_t)e0 * D_OUT + c);
    const float4 b1v = *(const float4*)(b2 + (size_t)e1 * D_OUT + c);
    float4 o;
    o.x = w0 * b0.x + w1 * b1v.x;
    o.y = w0 * b0.y + w1 * b1v.y;
    o.z = w0 * b0.z + w1 * b1v.z;
    o.w = w0 * b0.w + w1 * b1v.w;
    *(float4*)(out + (size_t)base) = o;
}

// ---------------------------------------------------------------------------
// Expert layer 1: hid[row][0..255] = relu(a[token(row)] @ W1[e] + b1[e])
// Grouped GEMM, gathered A rows, every tile single-expert (padding => -1 rows).
// ---------------------------------------------------------------------------
__global__ __launch_bounds__(256)
void expert1_kernel(const float* __restrict__ a, const float* __restrict__ W1,
                    const float* __restrict__ b1,
                    const int* __restrict__ assign_token, const int* __restrict__ offs,
                    float* __restrict__ hid)
{
    __shared__ float As[BK][BM + 4];
    __shared__ float Bs[BK][BN + 4];
    __shared__ int tok_sh[BM];

    const int tid  = threadIdx.x;
    const int tx   = tid & 15;
    const int ty   = tid >> 4;
    const int row0 = blockIdx.y * BM;
    const int col0 = blockIdx.x * BN;   // 0 or 128 (HID=256)

    int e = NEXP - 1;
    for (int q = 0; q < NEXP; ++q) { if (row0 < offs[q + 1]) { e = q; break; } }
    const float* B = W1 + (size_t)e * D_MODEL * HID;

    if (tid < BM) tok_sh[tid] = assign_token[row0 + tid];
    __syncthreads();

    float acc[8][8];
#pragma unroll
    for (int i = 0; i < 8; ++i)
#pragma unroll
        for (int j = 0; j < 8; ++j) acc[i][j] = 0.f;

    for (int k0 = 0; k0 < D_MODEL; k0 += BK) {
#pragma unroll
        for (int i = 0; i < 4; ++i) {
            int idx = tid + i * 256;
            int r = idx >> 3, c = idx & 7;
            int tok = tok_sh[r];
            As[c][r] = (tok >= 0) ? a[(size_t)tok * D_MODEL + k0 + c] : 0.f;
        }
#pragma unroll
        for (int i = 0; i < 4; ++i) {
            int idx = tid + i * 256;
            int r = idx >> 7, c = idx & 127;
            Bs[r][c] = B[(size_t)(k0 + r) * HID + col0 + c];
        }
        __syncthreads();
#pragma unroll
        for (int k = 0; k < BK; ++k) {
            float af[8], bf[8];
#pragma unroll
            for (int i = 0; i < 8; ++i) af[i] = As[k][ty * 8 + i];
#pragma unroll
            for (int j = 0; j < 8; ++j) bf[j] = Bs[k][tx * 8 + j];
#pragma unroll
            for (int i = 0; i < 8; ++i)
#pragma unroll
                for (int j = 0; j < 8; ++j) acc[i][j] += af[i] * bf[j];
        }
        __syncthreads();
    }

#pragma unroll
    for (int i = 0; i < 8; ++i) {
        int r = row0 + ty * 8 + i;
#pragma unroll
        for (int j = 0; j < 8; ++j) {
            int c = col0 + tx * 8 + j;
            float v = acc[i][j] + b1[(size_t)e * HID + c];
            hid[(size_t)r * HID + c] = fmaxf(v, 0.f);
        }
    }
}

// ---------------------------------------------------------------------------
// Expert layer 2: out[token(row)] += w(row) * (hid[row] @ W2[e])  (atomicAdd)
// ---------------------------------------------------------------------------
__global__ __launch_bounds__(256)
void expert2_kernel(const float* __restrict__ hid, const float* __restrict__ W2,
                    const int* __restrict__ assign_token, const float* __restrict__ assign_w,
                    const int* __restrict__ offs, float* __restrict__ out)
{
    __shared__ float As[BK][BM + 4];
    __shared__ float Bs[BK][BN + 4];
    __shared__ int   tok_sh[BM];
    __shared__ float w_sh[BM];

    const int tid  = threadIdx.x;
    const int tx   = tid & 15;
    const int ty   = tid >> 4;
    const int row0 = blockIdx.y * BM;
    const int col0 = blockIdx.x * BN;

    int e = NEXP - 1;
    for (int q = 0; q < NEXP; ++q) { if (row0 < offs[q + 1]) { e = q; break; } }
    const float* B = W2 + (size_t)e * HID * D_OUT;

    if (tid < BM) {
        tok_sh[tid] = assign_token[row0 + tid];
        w_sh[tid]   = assign_w[row0 + tid];
    }
    __syncthreads();

    float acc[8][8];
#pragma unroll
    for (int i = 0; i < 8; ++i)
#pragma unroll
        for (int j = 0; j < 8; ++j) acc[i][j] = 0.f;

    for (int k0 = 0; k0 < HID; k0 += BK) {
#pragma unroll
        for (int i = 0; i < 4; ++i) {
            int idx = tid + i * 256;
            int r = idx >> 3, c = idx & 7;
            As[c][r] = hid[(size_t)(row0 + r) * HID + k0 + c];
        }
#pragma unroll
        for (int i = 0; i < 4; ++i) {
            int idx = tid + i * 256;
            int r = idx >> 7, c = idx & 127;
            Bs[r][c] = B[(size_t)(k0 + r) * D_OUT + col0 + c];
        }
        __syncthreads();
#pragma unroll
        for (int k = 0; k < BK; ++k) {
            float af[8], bf[8];
#pragma unroll
            for (int i = 0; i < 8; ++i) af[i] = As[k][ty * 8 + i];
#pragma unroll
            for (int j = 0; j < 8; ++j) bf[j] = Bs[k][tx * 8 + j];
#pragma unroll
            for (int i = 0; i < 8; ++i)
#pragma unroll
                for (int j = 0; j < 8; ++j) acc[i][j] += af[i] * bf[j];
        }
        __syncthreads();
    }

#pragma unroll
    for (int i = 0; i < 8; ++i) {
        int tok = tok_sh[ty * 8 + i];
        if (tok < 0) continue;
        float w = w_sh[ty * 8 + i];
#pragma unroll
        for (int j = 0; j < 8; ++j) {
            int c = col0 + tx * 8 + j;
            atomicAdd(&out[(size_t)tok * D_OUT + c], w * acc[i][j]);
        }
    }
}

// ---------------------------------------------------------------------------
extern "C" void kernel_launch(void* const* d_in, const int* in_sizes, int n_in,
                              void* d_out, int out_size, void* d_ws, size_t ws_size,
                              hipStream_t stream)
{
    const float* x  = (const float*)d_in[0];
    // d_in[1] = top_k (always 2)
    const float* Wp = (const float*)d_in[2];
    const float* bp = (const float*)d_in[3];
    const float* Wv = (const float*)d_in[4];
    const float* bv = (const float*)d_in[5];
    const float* Wo = (const float*)d_in[6];
    const float* bo = (const float*)d_in[7];
    const float* Wg = (const float*)d_in[8];
    const float* bg = (const float*)d_in[9];
    const float* W1 = (const float*)d_in[10];
    const float* b1 = (const float*)d_in[11];
    const float* W2 = (const float*)d_in[12];
    const float* b2 = (const float*)d_in[13];
    float* out = (float*)d_out;

    // workspace layout (fp32 elements)
    float* h   = (float*)d_ws;                        // [N, D]   (also reused for a)
    float* hv  = h  + (size_t)N_TOK * D_MODEL;        // [N, D]
    float* hid = hv + (size_t)N_TOK * D_MODEL;        // [A_CAP, HID]
    int*   route_e      = (int*)(hid + (size_t)A_CAP * HID);  // [N,2]
    float* route_w      = (float*)(route_e + 2 * N_TOK);      // [N,2]
    int*   counts       = (int*)(route_w + 2 * N_TOK);        // [E]
    int*   offs         = counts + NEXP;                      // [E+1]
    int*   cursors      = offs + NEXP + 1;                    // [E]
    int*   assign_token = cursors + NEXP;                     // [A_CAP]
    float* assign_w     = (float*)(assign_token + A_CAP);     // [A_CAP]

    dim3 blk(256);
    dim3 gemm_grid(D_MODEL / BN, N_TOK / BM);   // (8, 128)

    // h = x@Wp + bp ; hv = h@Wv + bv ; a = hv@Wo + bo  (a overwrites h)
    sgemm_bias_kernel<<<gemm_grid, blk, 0, stream>>>(x,  Wp, bp, h,  D_IN,    D_MODEL);
    sgemm_bias_kernel<<<gemm_grid, blk, 0, stream>>>(h,  Wv, bv, hv, D_MODEL, D_MODEL);
    sgemm_bias_kernel<<<gemm_grid, blk, 0, stream>>>(hv, Wo, bo, h,  D_MODEL, D_MODEL);
    const float* a = h;

    init_kernel<<<(A_CAP + 255) / 256, blk, 0, stream>>>(counts, cursors, assign_token);
    gate_kernel<<<N_TOK / 4, blk, 0, stream>>>(a, Wg, bg, route_e, route_w, counts);
    offsets_kernel<<<1, 64, 0, stream>>>(counts, offs);
    scatter_kernel<<<(2 * N_TOK + 255) / 256, blk, 0, stream>>>(route_e, route_w, offs,
                                                                cursors, assign_token, assign_w);
    out_init_kernel<<<(N_TOK * D_OUT) / 1024, blk, 0, stream>>>(route_e, route_w, b2, out);

    expert1_kernel<<<dim3(HID / BN, A_CAP / BM), blk, 0, stream>>>(a, W1, b1,
                                                                   assign_token, offs, hid);
    expert2_kernel<<<dim3(D_OUT / BN, A_CAP / BM), blk, 0, stream>>>(hid, W2,
                                                                     assign_token, assign_w,
                                                                     offs, out);
}

// Round 2
// 2477.023 us; speedup vs baseline: 1.3144x; 1.3144x over previous
//
#include <hip/hip_runtime.h>
#include <hip/hip_bf16.h>
#include <math.h>

#define N_TOK   16384
#define D_IN    1024
#define D_MODEL 1024
#define HID     256
#define NEXP    10
#define D_OUT   1024

// GEMM tiling: 128x128 tile, BK=16, 256 threads, 8x8 micro-tile per thread.
// Fragment map: row = i*16+ty, col = j*16+tx  -> conflict-free LDS reads
// (16 consecutive banks across tx, broadcast across ty).
#define BM 128
#define BN 128
#define BK 16
#define LDA 20    // As row stride (floats): 16 + 4 pad
#define LDB 132   // Bs row stride (floats): 128 + 4 pad

// Expert routing: pad each expert's list to a multiple of EPAD so every
// 128-row tile is single-expert. Static capacity => static grid (graph-safe).
#define EPAD 128
#define A_CAP (2*N_TOK + NEXP*EPAD)   // 34048 = 266 * 128

// ---------------------------------------------------------------------------
// Dense fp32 GEMM with bias: C[M,N] = A[M,K] @ B[K,N] + bias[N]
// ---------------------------------------------------------------------------
__global__ __launch_bounds__(256)
void sgemm_bias_kernel(const float* __restrict__ A, const float* __restrict__ B,
                       const float* __restrict__ bias, float* __restrict__ C,
                       int K, int N)
{
    __shared__ float As[BM * LDA];
    __shared__ float Bs[BK * LDB];
    const int tid = threadIdx.x;
    const int tx = tid & 15, ty = tid >> 4;
    const int row0 = blockIdx.y * BM, col0 = blockIdx.x * BN;
    const int ar = tid >> 2, ac = (tid & 3) * 4;   // A staging: 4 lanes x 16B per row
    const int bk = tid >> 5, bc = (tid & 31) * 4;  // B staging: 32 lanes x 16B per row

    float acc[8][8] = {};

    for (int k0 = 0; k0 < K; k0 += BK) {
        float4 av0 = *(const float4*)(A + (size_t)(row0 + ar) * K + k0 + ac);
        float4 av1 = *(const float4*)(A + (size_t)(row0 + ar + 64) * K + k0 + ac);
        float4 bv0 = *(const float4*)(B + (size_t)(k0 + bk) * N + col0 + bc);
        float4 bv1 = *(const float4*)(B + (size_t)(k0 + bk + 8) * N + col0 + bc);
        __syncthreads();
        *(float4*)(&As[ar * LDA + ac]) = av0;
        *(float4*)(&As[(ar + 64) * LDA + ac]) = av1;
        *(float4*)(&Bs[bk * LDB + bc]) = bv0;
        *(float4*)(&Bs[(bk + 8) * LDB + bc]) = bv1;
        __syncthreads();
#pragma unroll
        for (int k = 0; k < BK; ++k) {
            float af[8], bf[8];
#pragma unroll
            for (int i = 0; i < 8; ++i) af[i] = As[(i * 16 + ty) * LDA + k];
#pragma unroll
            for (int j = 0; j < 8; ++j) bf[j] = Bs[k * LDB + j * 16 + tx];
#pragma unroll
            for (int i = 0; i < 8; ++i)
#pragma unroll
                for (int j = 0; j < 8; ++j) acc[i][j] = fmaf(af[i], bf[j], acc[i][j]);
        }
    }

#pragma unroll
    for (int i = 0; i < 8; ++i) {
        int r = row0 + i * 16 + ty;
#pragma unroll
        for (int j = 0; j < 8; ++j) {
            int c = col0 + j * 16 + tx;
            C[(size_t)r * N + c] = acc[i][j] + bias[c];
        }
    }
}

// ---------------------------------------------------------------------------
__global__ __launch_bounds__(256)
void init_kernel(int* __restrict__ counts, int* __restrict__ cursors,
                 int* __restrict__ assign_token)
{
    int i = blockIdx.x * 256 + threadIdx.x;
    if (i < NEXP) { counts[i] = 0; cursors[i] = 0; }
    if (i < A_CAP) assign_token[i] = -1;
}

// ---------------------------------------------------------------------------
// Gate: fp32 logits (must match numpy's fp32 top-2 routing), 1 wave/token.
// ---------------------------------------------------------------------------
__global__ __launch_bounds__(256)
void gate_kernel(const float* __restrict__ a, const float* __restrict__ Wg,
                 const float* __restrict__ bg,
                 int* __restrict__ route_e, float* __restrict__ route_w,
                 int* __restrict__ counts)
{
    const int wave = threadIdx.x >> 6;
    const int lane = threadIdx.x & 63;
    const int n = blockIdx.x * 4 + wave;

    float p[NEXP];
#pragma unroll
    for (int e = 0; e < NEXP; ++e) p[e] = 0.f;

    const float* arow = a + (size_t)n * D_MODEL;
    for (int d = lane; d < D_MODEL; d += 64) {
        float av = arow[d];
        const float* wgr = Wg + (size_t)d * NEXP;
#pragma unroll
        for (int e = 0; e < NEXP; ++e) p[e] += av * wgr[e];
    }
#pragma unroll
    for (int e = 0; e < NEXP; ++e) {
        float v = p[e];
        for (int off = 32; off > 0; off >>= 1) v += __shfl_down(v, off);
        p[e] = v;
    }
    if (lane == 0) {
        float lg[NEXP];
#pragma unroll
        for (int e = 0; e < NEXP; ++e) lg[e] = p[e] + bg[e];
        int e0 = 0; float v0 = lg[0];
        for (int e = 1; e < NEXP; ++e) if (lg[e] > v0) { v0 = lg[e]; e0 = e; }
        int e1 = -1; float v1 = -3.0e38f;
        for (int e = 0; e < NEXP; ++e) {
            if (e == e0) continue;
            if (lg[e] > v1) { v1 = lg[e]; e1 = e; }
        }
        float w0 = 1.f / (1.f + expf(v1 - v0));   // softmax + top-2 renorm
        float w1 = 1.f - w0;
        route_e[n * 2]     = e0;
        route_e[n * 2 + 1] = e1;
        route_w[n * 2]     = w0;
        route_w[n * 2 + 1] = w1;
        atomicAdd(&counts[e0], 1);
        atomicAdd(&counts[e1], 1);
    }
}

// ---------------------------------------------------------------------------
__global__ void offsets_kernel(const int* __restrict__ counts, int* __restrict__ offs)
{
    if (threadIdx.x == 0 && blockIdx.x == 0) {
        int acc = 0;
        for (int e = 0; e < NEXP; ++e) {
            offs[e] = acc;
            acc += (counts[e] + EPAD - 1) / EPAD * EPAD;
        }
        offs[NEXP] = acc;
    }
}

// ---------------------------------------------------------------------------
// Scatter assignments into expert-grouped padded lists; record slot per (n,k).
// ---------------------------------------------------------------------------
__global__ __launch_bounds__(256)
void scatter_kernel(const int* __restrict__ route_e,
                    const int* __restrict__ offs, int* __restrict__ cursors,
                    int* __restrict__ assign_token, int* __restrict__ slot_of)
{
    int i = blockIdx.x * 256 + threadIdx.x;
    if (i >= 2 * N_TOK) return;
    int e = route_e[i];
    int slot = offs[e] + atomicAdd(&cursors[e], 1);
    assign_token[slot] = i >> 1;
    slot_of[i] = slot;
}

// ---------------------------------------------------------------------------
// Expert layer 1: hid[row] = relu(a[token(row)] @ W1[e] + b1[e])  (fp32)
// ---------------------------------------------------------------------------
__global__ __launch_bounds__(256)
void expert1_kernel(const float* __restrict__ a, const float* __restrict__ W1,
                    const float* __restrict__ b1,
                    const int* __restrict__ assign_token, const int* __restrict__ offs,
                    float* __restrict__ hid)
{
    __shared__ float As[BM * LDA];
    __shared__ float Bs[BK * LDB];
    __shared__ int tok_sh[BM];

    const int tid = threadIdx.x;
    const int tx = tid & 15, ty = tid >> 4;
    const int row0 = blockIdx.y * BM, col0 = blockIdx.x * BN;  // col0: 0 or 128
    const int ar = tid >> 2, ac = (tid & 3) * 4;
    const int bk = tid >> 5, bc = (tid & 31) * 4;

    int e = NEXP - 1;
    for (int q = 0; q < NEXP; ++q) { if (row0 < offs[q + 1]) { e = q; break; } }
    const float* B = W1 + (size_t)e * D_MODEL * HID;

    if (tid < BM) tok_sh[tid] = assign_token[row0 + tid];
    __syncthreads();
    const int tok0 = tok_sh[ar], tok1 = tok_sh[ar + 64];
    const float4 z4 = make_float4(0.f, 0.f, 0.f, 0.f);

    float acc[8][8] = {};

    for (int k0 = 0; k0 < D_MODEL; k0 += BK) {
        float4 av0 = (tok0 >= 0) ? *(const float4*)(a + (size_t)tok0 * D_MODEL + k0 + ac) : z4;
        float4 av1 = (tok1 >= 0) ? *(const float4*)(a + (size_t)tok1 * D_MODEL + k0 + ac) : z4;
        float4 bv0 = *(const float4*)(B + (size_t)(k0 + bk) * HID + col0 + bc);
        float4 bv1 = *(const float4*)(B + (size_t)(k0 + bk + 8) * HID + col0 + bc);
        __syncthreads();
        *(float4*)(&As[ar * LDA + ac]) = av0;
        *(float4*)(&As[(ar + 64) * LDA + ac]) = av1;
        *(float4*)(&Bs[bk * LDB + bc]) = bv0;
        *(float4*)(&Bs[(bk + 8) * LDB + bc]) = bv1;
        __syncthreads();
#pragma unroll
        for (int k = 0; k < BK; ++k) {
            float af[8], bf[8];
#pragma unroll
            for (int i = 0; i < 8; ++i) af[i] = As[(i * 16 + ty) * LDA + k];
#pragma unroll
            for (int j = 0; j < 8; ++j) bf[j] = Bs[k * LDB + j * 16 + tx];
#pragma unroll
            for (int i = 0; i < 8; ++i)
#pragma unroll
                for (int j = 0; j < 8; ++j) acc[i][j] = fmaf(af[i], bf[j], acc[i][j]);
        }
    }

#pragma unroll
    for (int i = 0; i < 8; ++i) {
        int r = row0 + i * 16 + ty;
#pragma unroll
        for (int j = 0; j < 8; ++j) {
            int c = col0 + j * 16 + tx;
            float v = acc[i][j] + b1[(size_t)e * HID + c];
            hid[(size_t)r * HID + c] = fmaxf(v, 0.f);
        }
    }
}

// ---------------------------------------------------------------------------
// Expert layer 2: exp_out[row] = hid[row] @ W2[e]   (bf16 store, NO atomics)
// ---------------------------------------------------------------------------
__global__ __launch_bounds__(256)
void expert2_kernel(const float* __restrict__ hid, const float* __restrict__ W2,
                    const int* __restrict__ offs, __hip_bfloat16* __restrict__ exp_out)
{
    __shared__ float As[BM * LDA];
    __shared__ float Bs[BK * LDB];

    const int tid = threadIdx.x;
    const int tx = tid & 15, ty = tid >> 4;
    const int row0 = blockIdx.y * BM, col0 = blockIdx.x * BN;
    const int ar = tid >> 2, ac = (tid & 3) * 4;
    const int bk = tid >> 5, bc = (tid & 31) * 4;

    int e = NEXP - 1;
    for (int q = 0; q < NEXP; ++q) { if (row0 < offs[q + 1]) { e = q; break; } }
    const float* B = W2 + (size_t)e * HID * D_OUT;

    float acc[8][8] = {};

    for (int k0 = 0; k0 < HID; k0 += BK) {
        float4 av0 = *(const float4*)(hid + (size_t)(row0 + ar) * HID + k0 + ac);
        float4 av1 = *(const float4*)(hid + (size_t)(row0 + ar + 64) * HID + k0 + ac);
        float4 bv0 = *(const float4*)(B + (size_t)(k0 + bk) * D_OUT + col0 + bc);
        float4 bv1 = *(const float4*)(B + (size_t)(k0 + bk + 8) * D_OUT + col0 + bc);
        __syncthreads();
        *(float4*)(&As[ar * LDA + ac]) = av0;
        *(float4*)(&As[(ar + 64) * LDA + ac]) = av1;
        *(float4*)(&Bs[bk * LDB + bc]) = bv0;
        *(float4*)(&Bs[(bk + 8) * LDB + bc]) = bv1;
        __syncthreads();
#pragma unroll
        for (int k = 0; k < BK; ++k) {
            float af[8], bf[8];
#pragma unroll
            for (int i = 0; i < 8; ++i) af[i] = As[(i * 16 + ty) * LDA + k];
#pragma unroll
            for (int j = 0; j < 8; ++j) bf[j] = Bs[k * LDB + j * 16 + tx];
#pragma unroll
            for (int i = 0; i < 8; ++i)
#pragma unroll
                for (int j = 0; j < 8; ++j) acc[i][j] = fmaf(af[i], bf[j], acc[i][j]);
        }
    }

#pragma unroll
    for (int i = 0; i < 8; ++i) {
        int r = row0 + i * 16 + ty;
#pragma unroll
        for (int j = 0; j < 8; ++j) {
            int c = col0 + j * 16 + tx;
            exp_out[(size_t)r * D_OUT + c] = __float2bfloat16(acc[i][j]);
        }
    }
}

// ---------------------------------------------------------------------------
// Combine (gather): out[n] = w0*(row(s0)+b2[e0]) + w1*(row(s1)+b2[e1])
// One block per token, float4 per thread.
// ---------------------------------------------------------------------------
__global__ __launch_bounds__(256)
void combine_kernel(const __hip_bfloat16* __restrict__ exp_out,
                    const int* __restrict__ slot_of, const int* __restrict__ route_e,
                    const float* __restrict__ route_w, const float* __restrict__ b2,
                    float* __restrict__ out)
{
    const int n = blockIdx.x;
    const int c = threadIdx.x * 4;
    const int s0 = slot_of[n * 2],  s1 = slot_of[n * 2 + 1];
    const int e0 = route_e[n * 2],  e1 = route_e[n * 2 + 1];
    const float w0 = route_w[n * 2], w1 = route_w[n * 2 + 1];

    union U { float2 f2; __hip_bfloat16 b[4]; } u0, u1;
    u0.f2 = *(const float2*)(exp_out + (size_t)s0 * D_OUT + c);
    u1.f2 = *(const float2*)(exp_out + (size_t)s1 * D_OUT + c);
    const float4 bb0 = *(const float4*)(b2 + (size_t)e0 * D_OUT + c);
    const float4 bb1 = *(const float4*)(b2 + (size_t)e1 * D_OUT + c);

    float4 o;
    o.x = w0 * (__bfloat162float(u0.b[0]) + bb0.x) + w1 * (__bfloat162float(u1.b[0]) + bb1.x);
    o.y = w0 * (__bfloat162float(u0.b[1]) + bb0.y) + w1 * (__bfloat162float(u1.b[1]) + bb1.y);
    o.z = w0 * (__bfloat162float(u0.b[2]) + bb0.z) + w1 * (__bfloat162float(u1.b[2]) + bb1.z);
    o.w = w0 * (__bfloat162float(u0.b[3]) + bb0.w) + w1 * (__bfloat162float(u1.b[3]) + bb1.w);
    *(float4*)(out + (size_t)n * D_OUT + c) = o;
}

// ---------------------------------------------------------------------------
extern "C" void kernel_launch(void* const* d_in, const int* in_sizes, int n_in,
                              void* d_out, int out_size, void* d_ws, size_t ws_size,
                              hipStream_t stream)
{
    const float* x  = (const float*)d_in[0];
    const float* Wp = (const float*)d_in[2];
    const float* bp = (const float*)d_in[3];
    const float* Wv = (const float*)d_in[4];
    const float* bv = (const float*)d_in[5];
    const float* Wo = (const float*)d_in[6];
    const float* bo = (const float*)d_in[7];
    const float* Wg = (const float*)d_in[8];
    const float* bg = (const float*)d_in[9];
    const float* W1 = (const float*)d_in[10];
    const float* b1 = (const float*)d_in[11];
    const float* W2 = (const float*)d_in[12];
    const float* b2 = (const float*)d_in[13];
    float* out = (float*)d_out;

    // Workspace (fp32 elems). exp_out (bf16, 69.7 MB) aliases the h/hv region:
    // h ("a") is dead once expert1 finishes; expert2 is the only writer of exp_out.
    float* h   = (float*)d_ws;                         // [N,D] 64 MB (= "a")
    float* hv  = h + (size_t)N_TOK * D_MODEL;          // [N,D] 64 MB
    __hip_bfloat16* exp_out = (__hip_bfloat16*)d_ws;   // [A_CAP, D_OUT] bf16
    float* hid = hv + (size_t)N_TOK * D_MODEL;         // [A_CAP, HID] 34.9 MB
    int*   route_e      = (int*)(hid + (size_t)A_CAP * HID);
    float* route_w      = (float*)(route_e + 2 * N_TOK);
    int*   slot_of      = (int*)(route_w + 2 * N_TOK);
    int*   counts       = slot_of + 2 * N_TOK;
    int*   offs         = counts + NEXP;
    int*   cursors      = offs + NEXP + 1;
    int*   assign_token = cursors + NEXP;              // [A_CAP]

    dim3 blk(256);
    dim3 gemm_grid(D_MODEL / BN, N_TOK / BM);   // (8, 128)

    sgemm_bias_kernel<<<gemm_grid, blk, 0, stream>>>(x,  Wp, bp, h,  D_IN,    D_MODEL);
    sgemm_bias_kernel<<<gemm_grid, blk, 0, stream>>>(h,  Wv, bv, hv, D_MODEL, D_MODEL);
    sgemm_bias_kernel<<<gemm_grid, blk, 0, stream>>>(hv, Wo, bo, h,  D_MODEL, D_MODEL);
    const float* a = h;

    init_kernel<<<(A_CAP + 255) / 256, blk, 0, stream>>>(counts, cursors, assign_token);
    gate_kernel<<<N_TOK / 4, blk, 0, stream>>>(a, Wg, bg, route_e, route_w, counts);
    offsets_kernel<<<1, 64, 0, stream>>>(counts, offs);
    scatter_kernel<<<(2 * N_TOK + 255) / 256, blk, 0, stream>>>(route_e, offs, cursors,
                                                                assign_token, slot_of);

    expert1_kernel<<<dim3(HID / BN, A_CAP / BM), blk, 0, stream>>>(a, W1, b1,
                                                                   assign_token, offs, hid);
    expert2_kernel<<<dim3(D_OUT / BN, A_CAP / BM), blk, 0, stream>>>(hid, W2, offs, exp_out);
    combine_kernel<<<N_TOK, blk, 0, stream>>>(exp_out, slot_of, route_e, route_w, b2, out);
}

// Round 4
// 1161.130 us; speedup vs baseline: 2.8041x; 2.1333x over previous
//
#include <hip/hip_runtime.h>
#include <hip/hip_bf16.h>
#include <math.h>

#define N_TOK   16384
#define D_IN    1024
#define D_MODEL 1024
#define HID     256
#define NEXP    10
#define D_OUT   1024

// Expert routing: pad each expert's list to a multiple of EPAD so every
// 128-row tile is single-expert. Static capacity => static grid (graph-safe).
#define EPAD 128
#define A_CAP (2*N_TOK + NEXP*EPAD)   // 34048 = 266 * 128

typedef __attribute__((ext_vector_type(8))) __bf16 bf16x8;
typedef __attribute__((ext_vector_type(4))) float floatx4;

// ---------------------------------------------------------------------------
// LDS tile layout (per 128x64-short tile): row = 128 bytes = 8 chunks of 16B.
// Chunk g of row r is stored at position g ^ (r&7); staging applies the inverse
// swizzle on the per-lane *global* source address, so LDS dest is simply
// rowgroup_base + lane*16B (identical to what global_load_lds would write).
// ---------------------------------------------------------------------------
__device__ __forceinline__ bf16x8 lds_frag(const short* base, int row, int chunk)
{
    return *(const bf16x8*)(base + row * 64 + (chunk << 3));
}

// plain bf16: tile covers K-step 64 (chunks 0..7 = k 0..63)
__device__ __forceinline__ void tile_plain(const short* As, const short* Bs,
                                           int wm, int wn, int lane, floatx4 acc[4][4])
{
    const int m15 = lane & 15, quad = lane >> 4, sw = m15 & 7;
#pragma unroll
    for (int kk = 0; kk < 2; ++kk) {
        bf16x8 af[4], bfr[4];
#pragma unroll
        for (int i = 0; i < 4; ++i)
            af[i] = lds_frag(As, wm * 64 + i * 16 + m15, ((kk << 2) + quad) ^ sw);
#pragma unroll
        for (int j = 0; j < 4; ++j)
            bfr[j] = lds_frag(Bs, wn * 64 + j * 16 + m15, ((kk << 2) + quad) ^ sw);
#pragma unroll
        for (int i = 0; i < 4; ++i)
#pragma unroll
            for (int j = 0; j < 4; ++j)
                acc[i][j] = __builtin_amdgcn_mfma_f32_16x16x32_bf16(af[i], bfr[j],
                                                                    acc[i][j], 0, 0, 0);
    }
}

// split bf16: tile covers K-step 32; chunks 0..3 = hi plane, 4..7 = lo plane.
// acc += Ah*Bh + Ah*Bl + Al*Bh  (Al*Bl ~ 2^-18, dropped)
__device__ __forceinline__ void tile_split(const short* As, const short* Bs,
                                           int wm, int wn, int lane, floatx4 acc[4][4])
{
    const int m15 = lane & 15, quad = lane >> 4, sw = m15 & 7;
    bf16x8 ah[4], al[4], bh[4], bl[4];
#pragma unroll
    for (int i = 0; i < 4; ++i) {
        int r = wm * 64 + i * 16 + m15;
        ah[i] = lds_frag(As, r, quad ^ sw);
        al[i] = lds_frag(As, r, (4 + quad) ^ sw);
    }
#pragma unroll
    for (int j = 0; j < 4; ++j) {
        int r = wn * 64 + j * 16 + m15;
        bh[j] = lds_frag(Bs, r, quad ^ sw);
        bl[j] = lds_frag(Bs, r, (4 + quad) ^ sw);
    }
#pragma unroll
    for (int i = 0; i < 4; ++i)
#pragma unroll
        for (int j = 0; j < 4; ++j) {
            floatx4 c = acc[i][j];
            c = __builtin_amdgcn_mfma_f32_16x16x32_bf16(ah[i], bh[j], c, 0, 0, 0);
            c = __builtin_amdgcn_mfma_f32_16x16x32_bf16(ah[i], bl[j], c, 0, 0, 0);
            c = __builtin_amdgcn_mfma_f32_16x16x32_bf16(al[i], bh[j], c, 0, 0, 0);
            acc[i][j] = c;
        }
}

// ---------------------------------------------------------------------------
// Split-bf16 GEMM: C = A @ Bt^T + bias, inputs as hi/lo bf16 planes [M][K] and
// [N][K]; output hi (+ optional lo) bf16 planes. ~fp32 accuracy.
// Staging: register prefetch + 16B LDS stores (manual, graph/ISA-safe).
// ---------------------------------------------------------------------------
__global__ __launch_bounds__(256)
void gemm_split_kernel(const __hip_bfloat16* Ahi_, const __hip_bfloat16* Alo_,
                       const __hip_bfloat16* Bhi_, const __hip_bfloat16* Blo_,
                       const float* __restrict__ bias,
                       __hip_bfloat16* Chi_, __hip_bfloat16* Clo_, int K, int N)
{
    __shared__ __align__(16) short As[128 * 64];
    __shared__ __align__(16) short Bs[128 * 64];
    const short* Ahi = (const short*)Ahi_;
    const short* Alo = (const short*)Alo_;
    const short* Bhi = (const short*)Bhi_;
    const short* Blo = (const short*)Blo_;

    const int tid = threadIdx.x, lane = tid & 63, w = tid >> 6;
    const int wm = w & 1, wn = w >> 1;
    const int row0 = blockIdx.y * 128, col0 = blockIdx.x * 128;
    const int lr = lane >> 3;
    const int g = (lane & 7) ^ lr;          // swizzled source chunk (const per lane)
    const int plane = g >> 2, colel = (g & 3) * 8;

    const short* pA[4];
    const short* pB[4];
#pragma unroll
    for (int i = 0; i < 4; ++i) {
        int r = w * 32 + i * 8 + lr;
        pA[i] = (plane ? Alo : Ahi) + (size_t)(row0 + r) * K + colel;
        pB[i] = (plane ? Blo : Bhi) + (size_t)(col0 + r) * K + colel;
    }

    floatx4 acc[4][4];
#pragma unroll
    for (int i = 0; i < 4; ++i)
#pragma unroll
        for (int j = 0; j < 4; ++j) acc[i][j] = (floatx4)(0.f);

    for (int k0 = 0; k0 < K; k0 += 32) {
        bf16x8 va[4], vb[4];
#pragma unroll
        for (int i = 0; i < 4; ++i) {
            va[i] = *(const bf16x8*)(pA[i] + k0);
            vb[i] = *(const bf16x8*)(pB[i] + k0);
        }
        __syncthreads();
#pragma unroll
        for (int i = 0; i < 4; ++i) {
            *(bf16x8*)(&As[(w * 32 + i * 8) * 64 + lane * 8]) = va[i];
            *(bf16x8*)(&Bs[(w * 32 + i * 8) * 64 + lane * 8]) = vb[i];
        }
        __syncthreads();
        tile_split(As, Bs, wm, wn, lane, acc);
    }

    const int m15 = lane & 15, quad = lane >> 4;
#pragma unroll
    for (int i = 0; i < 4; ++i) {
#pragma unroll
        for (int t = 0; t < 4; ++t) {
            int row = row0 + wm * 64 + i * 16 + quad * 4 + t;
            size_t rb = (size_t)row * N;
#pragma unroll
            for (int j = 0; j < 4; ++j) {
                int col = col0 + wn * 64 + j * 16 + m15;
                float v = acc[i][j][t] + bias[col];
                __hip_bfloat16 hi = __float2bfloat16(v);
                Chi_[rb + col] = hi;
                if (Clo_) Clo_[rb + col] = __float2bfloat16(v - __bfloat162float(hi));
            }
        }
    }
}

// ---------------------------------------------------------------------------
// Expert layer 1: hid[slot] = relu(a[token(slot)] @ W1t[e]^T + b1[e])
// ---------------------------------------------------------------------------
__global__ __launch_bounds__(256)
void expert1_kernel(const __hip_bfloat16* a_, const __hip_bfloat16* W1t_,
                    const float* __restrict__ b1,
                    const int* __restrict__ assign_token, const int* __restrict__ offs,
                    const __hip_bfloat16* zrow_, __hip_bfloat16* hid_)
{
    __shared__ __align__(16) short As[128 * 64];
    __shared__ __align__(16) short Bs[128 * 64];
    const short* A = (const short*)a_;
    const short* zrow = (const short*)zrow_;

    const int tid = threadIdx.x, lane = tid & 63, w = tid >> 6;
    const int wm = w & 1, wn = w >> 1;
    const int row0 = blockIdx.y * 128, col0 = blockIdx.x * 128;   // col0: 0 or 128
    const int lr = lane >> 3, g = (lane & 7) ^ lr, colel = g * 8;

    int e = NEXP - 1;
    for (int q = 0; q < NEXP; ++q) { if (row0 < offs[q + 1]) { e = q; break; } }
    const short* B = (const short*)W1t_ + (size_t)e * HID * D_MODEL;

    const short* pA[4];
    const short* pB[4];
#pragma unroll
    for (int i = 0; i < 4; ++i) {
        int r = w * 32 + i * 8 + lr;
        int tok = assign_token[row0 + r];
        pA[i] = (tok >= 0 ? A + (size_t)tok * D_MODEL : zrow) + colel;
        pB[i] = B + (size_t)(col0 + r) * D_MODEL + colel;
    }

    floatx4 acc[4][4];
#pragma unroll
    for (int i = 0; i < 4; ++i)
#pragma unroll
        for (int j = 0; j < 4; ++j) acc[i][j] = (floatx4)(0.f);

    for (int k0 = 0; k0 < D_MODEL; k0 += 64) {
        bf16x8 va[4], vb[4];
#pragma unroll
        for (int i = 0; i < 4; ++i) {
            va[i] = *(const bf16x8*)(pA[i] + k0);
            vb[i] = *(const bf16x8*)(pB[i] + k0);
        }
        __syncthreads();
#pragma unroll
        for (int i = 0; i < 4; ++i) {
            *(bf16x8*)(&As[(w * 32 + i * 8) * 64 + lane * 8]) = va[i];
            *(bf16x8*)(&Bs[(w * 32 + i * 8) * 64 + lane * 8]) = vb[i];
        }
        __syncthreads();
        tile_plain(As, Bs, wm, wn, lane, acc);
    }

    const int m15 = lane & 15, quad = lane >> 4;
#pragma unroll
    for (int i = 0; i < 4; ++i) {
#pragma unroll
        for (int t = 0; t < 4; ++t) {
            int row = row0 + wm * 64 + i * 16 + quad * 4 + t;
            size_t rb = (size_t)row * HID;
#pragma unroll
            for (int j = 0; j < 4; ++j) {
                int col = col0 + wn * 64 + j * 16 + m15;
                float v = acc[i][j][t] + b1[(size_t)e * HID + col];
                hid_[rb + col] = __float2bfloat16(fmaxf(v, 0.f));
            }
        }
    }
}

// ---------------------------------------------------------------------------
// Expert layer 2: exp_out[slot] = hid[slot] @ W2t[e]^T
// ---------------------------------------------------------------------------
__global__ __launch_bounds__(256)
void expert2_kernel(const __hip_bfloat16* hid_, const __hip_bfloat16* W2t_,
                    const int* __restrict__ offs, __hip_bfloat16* exp_out_)
{
    __shared__ __align__(16) short As[128 * 64];
    __shared__ __align__(16) short Bs[128 * 64];
    const short* A = (const short*)hid_;

    const int tid = threadIdx.x, lane = tid & 63, w = tid >> 6;
    const int wm = w & 1, wn = w >> 1;
    const int row0 = blockIdx.y * 128, col0 = blockIdx.x * 128;
    const int lr = lane >> 3, g = (lane & 7) ^ lr, colel = g * 8;

    int e = NEXP - 1;
    for (int q = 0; q < NEXP; ++q) { if (row0 < offs[q + 1]) { e = q; break; } }
    const short* B = (const short*)W2t_ + (size_t)e * D_OUT * HID;

    const short* pA[4];
    const short* pB[4];
#pragma unroll
    for (int i = 0; i < 4; ++i) {
        int r = w * 32 + i * 8 + lr;
        pA[i] = A + (size_t)(row0 + r) * HID + colel;
        pB[i] = B + (size_t)(col0 + r) * HID + colel;
    }

    floatx4 acc[4][4];
#pragma unroll
    for (int i = 0; i < 4; ++i)
#pragma unroll
        for (int j = 0; j < 4; ++j) acc[i][j] = (floatx4)(0.f);

    for (int k0 = 0; k0 < HID; k0 += 64) {
        bf16x8 va[4], vb[4];
#pragma unroll
        for (int i = 0; i < 4; ++i) {
            va[i] = *(const bf16x8*)(pA[i] + k0);
            vb[i] = *(const bf16x8*)(pB[i] + k0);
        }
        __syncthreads();
#pragma unroll
        for (int i = 0; i < 4; ++i) {
            *(bf16x8*)(&As[(w * 32 + i * 8) * 64 + lane * 8]) = va[i];
            *(bf16x8*)(&Bs[(w * 32 + i * 8) * 64 + lane * 8]) = vb[i];
        }
        __syncthreads();
        tile_plain(As, Bs, wm, wn, lane, acc);
    }

    const int m15 = lane & 15, quad = lane >> 4;
#pragma unroll
    for (int i = 0; i < 4; ++i) {
#pragma unroll
        for (int t = 0; t < 4; ++t) {
            int row = row0 + wm * 64 + i * 16 + quad * 4 + t;
            size_t rb = (size_t)row * D_OUT;
#pragma unroll
            for (int j = 0; j < 4; ++j) {
                int col = col0 + wn * 64 + j * 16 + m15;
                exp_out_[rb + col] = __float2bfloat16(acc[i][j][t]);
            }
        }
    }
}

// ---------------------------------------------------------------------------
// x -> hi/lo bf16 planes (float4 loads, short4 stores)
// ---------------------------------------------------------------------------
__global__ __launch_bounds__(256)
void convert_split_kernel(const float* __restrict__ x,
                          __hip_bfloat16* __restrict__ hi, __hip_bfloat16* __restrict__ lo)
{
    size_t base = ((size_t)blockIdx.x * 256 + threadIdx.x) * 4;
    float4 v = *(const float4*)(x + base);
    union { __hip_bfloat16 b[4]; short4 s; } uh, ul;
    uh.b[0] = __float2bfloat16(v.x); ul.b[0] = __float2bfloat16(v.x - __bfloat162float(uh.b[0]));
    uh.b[1] = __float2bfloat16(v.y); ul.b[1] = __float2bfloat16(v.y - __bfloat162float(uh.b[1]));
    uh.b[2] = __float2bfloat16(v.z); ul.b[2] = __float2bfloat16(v.z - __bfloat162float(uh.b[2]));
    uh.b[3] = __float2bfloat16(v.w); ul.b[3] = __float2bfloat16(v.w - __bfloat162float(uh.b[3]));
    *(short4*)(hi + base) = uh.s;
    *(short4*)(lo + base) = ul.s;
}

// ---------------------------------------------------------------------------
// fp32 [R][C] -> transposed bf16 [C][R] hi (+ optional lo); batched over z.
// ---------------------------------------------------------------------------
__global__ __launch_bounds__(256)
void transpose_cvt_kernel(const float* __restrict__ in, __hip_bfloat16* out_hi,
                          __hip_bfloat16* out_lo, int R, int C)
{
    __shared__ float t[32][33];
    const size_t zoff = (size_t)blockIdx.z * R * C;
    in += zoff; out_hi += zoff; if (out_lo) out_lo += zoff;
    const int c0 = blockIdx.x * 32, r0 = blockIdx.y * 32;
    const int tx = threadIdx.x & 31, ty = threadIdx.x >> 5;
#pragma unroll
    for (int i = 0; i < 4; ++i)
        t[ty + i * 8][tx] = in[(size_t)(r0 + ty + i * 8) * C + (c0 + tx)];
    __syncthreads();
#pragma unroll
    for (int i = 0; i < 4; ++i) {
        float v = t[tx][ty + i * 8];
        size_t o = (size_t)(c0 + ty + i * 8) * R + (r0 + tx);
        __hip_bfloat16 hi = __float2bfloat16(v);
        out_hi[o] = hi;
        if (out_lo) out_lo[o] = __float2bfloat16(v - __bfloat162float(hi));
    }
}

// ---------------------------------------------------------------------------
// Thin fp32 GEMM for gate-matrix chain: Cm[1024][10] = A[1024][1024] @ B[1024][10]
// ---------------------------------------------------------------------------
__global__ __launch_bounds__(256)
void wchain_kernel(const float* __restrict__ A, const float* __restrict__ B,
                   float* __restrict__ Cm)
{
    const int wave = threadIdx.x >> 6, lane = threadIdx.x & 63;
    const int m = blockIdx.x * 4 + wave;
    float acc[NEXP];
#pragma unroll
    for (int e = 0; e < NEXP; ++e) acc[e] = 0.f;
    const float* ar = A + (size_t)m * 1024;
    for (int d = lane; d < 1024; d += 64) {
        float av = ar[d];
        const float* br = B + (size_t)d * NEXP;
#pragma unroll
        for (int e = 0; e < NEXP; ++e) acc[e] += av * br[e];
    }
#pragma unroll
    for (int e = 0; e < NEXP; ++e) {
        float v = acc[e];
        for (int off = 32; off > 0; off >>= 1) v += __shfl_down(v, off);
        if (lane == 0) Cm[(size_t)m * NEXP + e] = v;
    }
}

// ---------------------------------------------------------------------------
// bg_eff = bg + bo@Wg + bv@t1 + bp@t2    (single block)
// ---------------------------------------------------------------------------
__global__ __launch_bounds__(256)
void bias_eff_kernel(const float* __restrict__ bp, const float* __restrict__ bv,
                     const float* __restrict__ bo, const float* __restrict__ bg,
                     const float* __restrict__ Wg, const float* __restrict__ t1,
                     const float* __restrict__ t2, float* __restrict__ bgeff)
{
    __shared__ float red[256];
    const int tid = threadIdx.x;
    float acc[NEXP];
#pragma unroll
    for (int e = 0; e < NEXP; ++e) acc[e] = 0.f;
    for (int d = tid; d < 1024; d += 256) {
        float o = bo[d], v = bv[d], p = bp[d];
#pragma unroll
        for (int e = 0; e < NEXP; ++e)
            acc[e] += o * Wg[d * NEXP + e] + v * t1[d * NEXP + e] + p * t2[d * NEXP + e];
    }
    for (int e = 0; e < NEXP; ++e) {
        red[tid] = acc[e];
        __syncthreads();
        for (int s = 128; s > 0; s >>= 1) {
            if (tid < s) red[tid] += red[tid + s];
            __syncthreads();
        }
        if (tid == 0) bgeff[e] = red[0] + bg[e];
        __syncthreads();
    }
}

// ---------------------------------------------------------------------------
// Gate from fp32 x and fused matrix Mg [D_IN][10]: exact-fp32-class routing.
// ---------------------------------------------------------------------------
__global__ __launch_bounds__(256)
void gate_kernel(const float* __restrict__ x, const float* __restrict__ Mg,
                 const float* __restrict__ bgeff,
                 int* __restrict__ route_e, float* __restrict__ route_w,
                 int* __restrict__ counts)
{
    const int wave = threadIdx.x >> 6;
    const int lane = threadIdx.x & 63;
    const int n = blockIdx.x * 4 + wave;

    float p[NEXP];
#pragma unroll
    for (int e = 0; e < NEXP; ++e) p[e] = 0.f;

    const float* xrow = x + (size_t)n * D_IN;
    for (int d = lane; d < D_IN; d += 64) {
        float av = xrow[d];
        const float* mr = Mg + (size_t)d * NEXP;
#pragma unroll
        for (int e = 0; e < NEXP; ++e) p[e] += av * mr[e];
    }
#pragma unroll
    for (int e = 0; e < NEXP; ++e) {
        float v = p[e];
        for (int off = 32; off > 0; off >>= 1) v += __shfl_down(v, off);
        p[e] = v;
    }
    if (lane == 0) {
        float lg[NEXP];
#pragma unroll
        for (int e = 0; e < NEXP; ++e) lg[e] = p[e] + bgeff[e];
        int e0 = 0; float v0 = lg[0];
        for (int e = 1; e < NEXP; ++e) if (lg[e] > v0) { v0 = lg[e]; e0 = e; }
        int e1 = -1; float v1 = -3.0e38f;
        for (int e = 0; e < NEXP; ++e) {
            if (e == e0) continue;
            if (lg[e] > v1) { v1 = lg[e]; e1 = e; }
        }
        float w0 = 1.f / (1.f + expf(v1 - v0));   // softmax + top-2 renorm
        float w1 = 1.f - w0;
        route_e[n * 2]     = e0;
        route_e[n * 2 + 1] = e1;
        route_w[n * 2]     = w0;
        route_w[n * 2 + 1] = w1;
        atomicAdd(&counts[e0], 1);
        atomicAdd(&counts[e1], 1);
    }
}

// ---------------------------------------------------------------------------
__global__ __launch_bounds__(256)
void init_kernel(int* __restrict__ counts, int* __restrict__ cursors,
                 int* __restrict__ assign_token, int* __restrict__ zrow_i)
{
    int i = blockIdx.x * 256 + threadIdx.x;
    if (i < NEXP) { counts[i] = 0; cursors[i] = 0; }
    if (i < 512) zrow_i[i] = 0;                 // 1024 bf16 zeros
    if (i < A_CAP) assign_token[i] = -1;
}

__global__ void offsets_kernel(const int* __restrict__ counts, int* __restrict__ offs)
{
    if (threadIdx.x == 0 && blockIdx.x == 0) {
        int acc = 0;
        for (int e = 0; e < NEXP; ++e) {
            offs[e] = acc;
            acc += (counts[e] + EPAD - 1) / EPAD * EPAD;
        }
        offs[NEXP] = acc;
    }
}

__global__ __launch_bounds__(256)
void scatter_kernel(const int* __restrict__ route_e,
                    const int* __restrict__ offs, int* __restrict__ cursors,
                    int* __restrict__ assign_token, int* __restrict__ slot_of)
{
    int i = blockIdx.x * 256 + threadIdx.x;
    if (i >= 2 * N_TOK) return;
    int e = route_e[i];
    int slot = offs[e] + atomicAdd(&cursors[e], 1);
    assign_token[slot] = i >> 1;
    slot_of[i] = slot;
}

// ---------------------------------------------------------------------------
// Combine (gather): out[n] = w0*(row(s0)+b2[e0]) + w1*(row(s1)+b2[e1])
// ---------------------------------------------------------------------------
__global__ __launch_bounds__(256)
void combine_kernel(const __hip_bfloat16* __restrict__ exp_out,
                    const int* __restrict__ slot_of, const int* __restrict__ route_e,
                    const float* __restrict__ route_w, const float* __restrict__ b2,
                    float* __restrict__ out)
{
    const int n = blockIdx.x;
    const int c = threadIdx.x * 4;
    const int s0 = slot_of[n * 2],  s1 = slot_of[n * 2 + 1];
    const int e0 = route_e[n * 2],  e1 = route_e[n * 2 + 1];
    const float w0 = route_w[n * 2], w1 = route_w[n * 2 + 1];

    union U { float2 f2; __hip_bfloat16 b[4]; } u0, u1;
    u0.f2 = *(const float2*)(exp_out + (size_t)s0 * D_OUT + c);
    u1.f2 = *(const float2*)(exp_out + (size_t)s1 * D_OUT + c);
    const float4 bb0 = *(const float4*)(b2 + (size_t)e0 * D_OUT + c);
    const float4 bb1 = *(const float4*)(b2 + (size_t)e1 * D_OUT + c);

    float4 o;
    o.x = w0 * (__bfloat162float(u0.b[0]) + bb0.x) + w1 * (__bfloat162float(u1.b[0]) + bb1.x);
    o.y = w0 * (__bfloat162float(u0.b[1]) + bb0.y) + w1 * (__bfloat162float(u1.b[1]) + bb1.y);
    o.z = w0 * (__bfloat162float(u0.b[2]) + bb0.z) + w1 * (__bfloat162float(u1.b[2]) + bb1.z);
    o.w = w0 * (__bfloat162float(u0.b[3]) + bb0.w) + w1 * (__bfloat162float(u1.b[3]) + bb1.w);
    *(float4*)(out + (size_t)n * D_OUT + c) = o;
}

// ---------------------------------------------------------------------------
extern "C" void kernel_launch(void* const* d_in, const int* in_sizes, int n_in,
                              void* d_out, int out_size, void* d_ws, size_t ws_size,
                              hipStream_t stream)
{
    const float* x  = (const float*)d_in[0];
    const float* Wp = (const float*)d_in[2];
    const float* bp = (const float*)d_in[3];
    const float* Wv = (const float*)d_in[4];
    const float* bv = (const float*)d_in[5];
    const float* Wo = (const float*)d_in[6];
    const float* bo = (const float*)d_in[7];
    const float* Wg = (const float*)d_in[8];
    const float* bg = (const float*)d_in[9];
    const float* W1 = (const float*)d_in[10];
    const float* b1 = (const float*)d_in[11];
    const float* W2 = (const float*)d_in[12];
    const float* b2 = (const float*)d_in[13];
    float* out = (float*)d_out;

    // ---- workspace layout (bytes); lifetime-based aliasing, total ~150.6 MiB ----
    char* W = (char*)d_ws;
    typedef __hip_bfloat16 bf;
    bf* x_hi  = (bf*)(W + 0);                  // [N,D]  dead after gemm1
    bf* x_lo  = (bf*)(W + 33554432);           //        dead after gemm1
    bf* h_hi  = (bf*)(W + 67108864);           // dead after gemm2
    bf* h_lo  = (bf*)(W + 100663296);          // dead after gemm2
    bf* hv_hi = (bf*)(W + 0);                  // aliases x (dead) ; dead after gemm3
    bf* hv_lo = (bf*)(W + 33554432);
    bf* a_bf  = (bf*)(W + 100663296);          // aliases h_lo (dead); read by expert1
    bf* exp_out = (bf*)(W + 0);                // [A_CAP,D_OUT] 69.7MB; hv dead by then
    bf* hid   = (bf*)(W + 69730304);           // [A_CAP,HID] in dead h_hi region
    // weights (alive whole run)
    bf* Wpt_hi = (bf*)(W + 134217728);
    bf* Wpt_lo = (bf*)(W + 136314880);
    bf* Wvt_hi = (bf*)(W + 138412032);
    bf* Wvt_lo = (bf*)(W + 140509184);
    bf* Wot_hi = (bf*)(W + 142606336);
    bf* Wot_lo = (bf*)(W + 144703488);
    bf* W1t    = (bf*)(W + 146800640);         // [E][HID][D]
    bf* W2t    = (bf*)(W + 152043520);         // [E][D_OUT][HID]
    // small buffers
    bf*    zrow         = (bf*)(W + 157286400);       // 1024 bf16 zeros
    int*   route_e      = (int*)(W + 157288448);
    float* route_w      = (float*)(W + 157419520);
    int*   slot_of      = (int*)(W + 157550592);
    int*   assign_token = (int*)(W + 157681664);
    int*   counts       = (int*)(W + 157817856);
    int*   offs         = (int*)(W + 157817920);
    int*   cursors      = (int*)(W + 157817984);
    float* Mg           = (float*)(W + 157818048);
    float* t1           = (float*)(W + 157859008);
    float* t2           = (float*)(W + 157899968);
    float* bgeff        = (float*)(W + 157940928);

    dim3 blk(256);

    // ---- conversions ----
    convert_split_kernel<<<(N_TOK * D_IN) / 1024, blk, 0, stream>>>(x, x_hi, x_lo);
    transpose_cvt_kernel<<<dim3(32, 32, 1), blk, 0, stream>>>(Wp, Wpt_hi, Wpt_lo, D_IN, D_MODEL);
    transpose_cvt_kernel<<<dim3(32, 32, 1), blk, 0, stream>>>(Wv, Wvt_hi, Wvt_lo, D_MODEL, D_MODEL);
    transpose_cvt_kernel<<<dim3(32, 32, 1), blk, 0, stream>>>(Wo, Wot_hi, Wot_lo, D_MODEL, D_MODEL);
    transpose_cvt_kernel<<<dim3(HID / 32, D_MODEL / 32, NEXP), blk, 0, stream>>>(W1, W1t, nullptr, D_MODEL, HID);
    transpose_cvt_kernel<<<dim3(D_OUT / 32, HID / 32, NEXP), blk, 0, stream>>>(W2, W2t, nullptr, HID, D_OUT);

    // ---- gate matrix chain (fp32, exactness-preserving associativity) ----
    wchain_kernel<<<256, blk, 0, stream>>>(Wo, Wg, t1);    // t1 = Wo@Wg
    wchain_kernel<<<256, blk, 0, stream>>>(Wv, t1, t2);    // t2 = Wv@t1
    wchain_kernel<<<256, blk, 0, stream>>>(Wp, t2, Mg);    // Mg = Wp@t2
    bias_eff_kernel<<<1, blk, 0, stream>>>(bp, bv, bo, bg, Wg, t1, t2, bgeff);

    // ---- routing ----
    init_kernel<<<(A_CAP + 255) / 256, blk, 0, stream>>>(counts, cursors, assign_token,
                                                         (int*)zrow);
    gate_kernel<<<N_TOK / 4, blk, 0, stream>>>(x, Mg, bgeff, route_e, route_w, counts);
    offsets_kernel<<<1, 64, 0, stream>>>(counts, offs);
    scatter_kernel<<<(2 * N_TOK + 255) / 256, blk, 0, stream>>>(route_e, offs, cursors,
                                                                assign_token, slot_of);

    // ---- main chain: split-bf16 MFMA (~fp32 accuracy) ----
    dim3 cgrid(D_MODEL / 128, N_TOK / 128);   // (8, 128)
    gemm_split_kernel<<<cgrid, blk, 0, stream>>>(x_hi, x_lo, Wpt_hi, Wpt_lo, bp,
                                                 h_hi, h_lo, D_IN, D_MODEL);
    gemm_split_kernel<<<cgrid, blk, 0, stream>>>(h_hi, h_lo, Wvt_hi, Wvt_lo, bv,
                                                 hv_hi, hv_lo, D_MODEL, D_MODEL);
    gemm_split_kernel<<<cgrid, blk, 0, stream>>>(hv_hi, hv_lo, Wot_hi, Wot_lo, bo,
                                                 a_bf, nullptr, D_MODEL, D_MODEL);

    // ---- experts: plain bf16 MFMA, grouped by expert ----
    expert1_kernel<<<dim3(HID / 128, A_CAP / 128), blk, 0, stream>>>(
        a_bf, W1t, b1, assign_token, offs, zrow, hid);
    expert2_kernel<<<dim3(D_OUT / 128, A_CAP / 128), blk, 0, stream>>>(
        hid, W2t, offs, exp_out);
    combine_kernel<<<N_TOK, blk, 0, stream>>>(exp_out, slot_of, route_e, route_w, b2, out);
}

// Round 5
// 1112.683 us; speedup vs baseline: 2.9262x; 1.0435x over previous
//
#include <hip/hip_runtime.h>
#include <hip/hip_bf16.h>
#include <math.h>

#define N_TOK   16384
#define D_IN    1024
#define D_MODEL 1024
#define HID     256
#define NEXP    10
#define D_OUT   1024

// Expert routing: pad each expert's list to a multiple of EPAD so every
// 128-row tile is single-expert. Static capacity => static grid (graph-safe).
#define EPAD 128
#define A_CAP (2*N_TOK + NEXP*EPAD)   // 34048 = 266 * 128

typedef __attribute__((ext_vector_type(8))) __bf16 bf16x8;
typedef __attribute__((ext_vector_type(4))) float floatx4;

// ---------------------------------------------------------------------------
// LDS tile layout (per 128x64-short tile): row = 128 bytes = 8 chunks of 16B.
// Chunk g of row r is stored at position g ^ (r&7); staging applies the inverse
// swizzle on the per-lane *global* source address, so the LDS store is simply
// rowgroup_base + lane*16B. (VGPR round-trip staging: R3 proved global_load_lds
// faults in this configuration; R4 proved this variant correct.)
// ---------------------------------------------------------------------------
__device__ __forceinline__ bf16x8 lds_frag(const short* base, int row, int chunk)
{
    return *(const bf16x8*)(base + row * 64 + (chunk << 3));
}

// plain bf16: tile covers K-step 64 (chunks 0..7 = k 0..63)
__device__ __forceinline__ void tile_plain(const short* As, const short* Bs,
                                           int wm, int wn, int lane, floatx4 acc[4][4])
{
    const int m15 = lane & 15, quad = lane >> 4, sw = m15 & 7;
#pragma unroll
    for (int kk = 0; kk < 2; ++kk) {
        bf16x8 af[4], bfr[4];
#pragma unroll
        for (int i = 0; i < 4; ++i)
            af[i] = lds_frag(As, wm * 64 + i * 16 + m15, ((kk << 2) + quad) ^ sw);
#pragma unroll
        for (int j = 0; j < 4; ++j)
            bfr[j] = lds_frag(Bs, wn * 64 + j * 16 + m15, ((kk << 2) + quad) ^ sw);
#pragma unroll
        for (int i = 0; i < 4; ++i)
#pragma unroll
            for (int j = 0; j < 4; ++j)
                acc[i][j] = __builtin_amdgcn_mfma_f32_16x16x32_bf16(af[i], bfr[j],
                                                                    acc[i][j], 0, 0, 0);
    }
}

// split bf16: tile covers K-step 32; chunks 0..3 = hi plane, 4..7 = lo plane.
// acc += Ah*Bh + Ah*Bl + Al*Bh  (Al*Bl ~ 2^-18, dropped)
__device__ __forceinline__ void tile_split(const short* As, const short* Bs,
                                           int wm, int wn, int lane, floatx4 acc[4][4])
{
    const int m15 = lane & 15, quad = lane >> 4, sw = m15 & 7;
    bf16x8 ah[4], al[4], bh[4], bl[4];
#pragma unroll
    for (int i = 0; i < 4; ++i) {
        int r = wm * 64 + i * 16 + m15;
        ah[i] = lds_frag(As, r, quad ^ sw);
        al[i] = lds_frag(As, r, (4 + quad) ^ sw);
    }
#pragma unroll
    for (int j = 0; j < 4; ++j) {
        int r = wn * 64 + j * 16 + m15;
        bh[j] = lds_frag(Bs, r, quad ^ sw);
        bl[j] = lds_frag(Bs, r, (4 + quad) ^ sw);
    }
#pragma unroll
    for (int i = 0; i < 4; ++i)
#pragma unroll
        for (int j = 0; j < 4; ++j) {
            floatx4 c = acc[i][j];
            c = __builtin_amdgcn_mfma_f32_16x16x32_bf16(ah[i], bh[j], c, 0, 0, 0);
            c = __builtin_amdgcn_mfma_f32_16x16x32_bf16(ah[i], bl[j], c, 0, 0, 0);
            c = __builtin_amdgcn_mfma_f32_16x16x32_bf16(al[i], bh[j], c, 0, 0, 0);
            acc[i][j] = c;
        }
}

// ---------------------------------------------------------------------------
// Split-bf16 GEMM: C = A @ Bt^T + bias, inputs as hi/lo bf16 planes [M][K] and
// [N][K]; output hi (+ optional lo) bf16 planes. ~fp32 accuracy.
// ---------------------------------------------------------------------------
__global__ __launch_bounds__(256)
void gemm_split_kernel(const __hip_bfloat16* Ahi_, const __hip_bfloat16* Alo_,
                       const __hip_bfloat16* Bhi_, const __hip_bfloat16* Blo_,
                       const float* __restrict__ bias,
                       __hip_bfloat16* Chi_, __hip_bfloat16* Clo_, int K, int N)
{
    __shared__ __align__(16) short As[128 * 64];
    __shared__ __align__(16) short Bs[128 * 64];
    const short* Ahi = (const short*)Ahi_;
    const short* Alo = (const short*)Alo_;
    const short* Bhi = (const short*)Bhi_;
    const short* Blo = (const short*)Blo_;

    const int tid = threadIdx.x, lane = tid & 63, w = tid >> 6;
    const int wm = w & 1, wn = w >> 1;
    const int row0 = blockIdx.y * 128, col0 = blockIdx.x * 128;
    const int lr = lane >> 3;
    const int g = (lane & 7) ^ lr;          // swizzled source chunk (const per lane)
    const int plane = g >> 2, colel = (g & 3) * 8;

    const short* pA[4];
    const short* pB[4];
#pragma unroll
    for (int i = 0; i < 4; ++i) {
        int r = w * 32 + i * 8 + lr;
        pA[i] = (plane ? Alo : Ahi) + (size_t)(row0 + r) * K + colel;
        pB[i] = (plane ? Blo : Bhi) + (size_t)(col0 + r) * K + colel;
    }

    floatx4 acc[4][4];
#pragma unroll
    for (int i = 0; i < 4; ++i)
#pragma unroll
        for (int j = 0; j < 4; ++j) acc[i][j] = (floatx4)(0.f);

    for (int k0 = 0; k0 < K; k0 += 32) {
        bf16x8 va[4], vb[4];
#pragma unroll
        for (int i = 0; i < 4; ++i) {
            va[i] = *(const bf16x8*)(pA[i] + k0);
            vb[i] = *(const bf16x8*)(pB[i] + k0);
        }
        __syncthreads();
#pragma unroll
        for (int i = 0; i < 4; ++i) {
            *(bf16x8*)(&As[(w * 32 + i * 8) * 64 + lane * 8]) = va[i];
            *(bf16x8*)(&Bs[(w * 32 + i * 8) * 64 + lane * 8]) = vb[i];
        }
        __syncthreads();
        tile_split(As, Bs, wm, wn, lane, acc);
    }

    const int m15 = lane & 15, quad = lane >> 4;
#pragma unroll
    for (int i = 0; i < 4; ++i) {
#pragma unroll
        for (int t = 0; t < 4; ++t) {
            int row = row0 + wm * 64 + i * 16 + quad * 4 + t;
            size_t rb = (size_t)row * N;
#pragma unroll
            for (int j = 0; j < 4; ++j) {
                int col = col0 + wn * 64 + j * 16 + m15;
                float v = acc[i][j][t] + bias[col];
                __hip_bfloat16 hi = __float2bfloat16(v);
                Chi_[rb + col] = hi;
                if (Clo_) Clo_[rb + col] = __float2bfloat16(v - __bfloat162float(hi));
            }
        }
    }
}

// ---------------------------------------------------------------------------
// Expert layer 1: hid[slot] = relu(a[token(slot)] @ W1t[e]^T + b1[e])
// ---------------------------------------------------------------------------
__global__ __launch_bounds__(256)
void expert1_kernel(const __hip_bfloat16* a_, const __hip_bfloat16* W1t_,
                    const float* __restrict__ b1,
                    const int* __restrict__ assign_token, const int* __restrict__ offs,
                    const __hip_bfloat16* zrow_, __hip_bfloat16* hid_)
{
    __shared__ __align__(16) short As[128 * 64];
    __shared__ __align__(16) short Bs[128 * 64];
    const short* A = (const short*)a_;
    const short* zrow = (const short*)zrow_;

    const int tid = threadIdx.x, lane = tid & 63, w = tid >> 6;
    const int wm = w & 1, wn = w >> 1;
    const int row0 = blockIdx.y * 128, col0 = blockIdx.x * 128;   // col0: 0 or 128
    const int lr = lane >> 3, g = (lane & 7) ^ lr, colel = g * 8;

    int e = NEXP - 1;
    for (int q = 0; q < NEXP; ++q) { if (row0 < offs[q + 1]) { e = q; break; } }
    const short* B = (const short*)W1t_ + (size_t)e * HID * D_MODEL;

    const short* pA[4];
    const short* pB[4];
#pragma unroll
    for (int i = 0; i < 4; ++i) {
        int r = w * 32 + i * 8 + lr;
        int tok = assign_token[row0 + r];
        pA[i] = (tok >= 0 ? A + (size_t)tok * D_MODEL : zrow) + colel;
        pB[i] = B + (size_t)(col0 + r) * D_MODEL + colel;
    }

    floatx4 acc[4][4];
#pragma unroll
    for (int i = 0; i < 4; ++i)
#pragma unroll
        for (int j = 0; j < 4; ++j) acc[i][j] = (floatx4)(0.f);

    for (int k0 = 0; k0 < D_MODEL; k0 += 64) {
        bf16x8 va[4], vb[4];
#pragma unroll
        for (int i = 0; i < 4; ++i) {
            va[i] = *(const bf16x8*)(pA[i] + k0);
            vb[i] = *(const bf16x8*)(pB[i] + k0);
        }
        __syncthreads();
#pragma unroll
        for (int i = 0; i < 4; ++i) {
            *(bf16x8*)(&As[(w * 32 + i * 8) * 64 + lane * 8]) = va[i];
            *(bf16x8*)(&Bs[(w * 32 + i * 8) * 64 + lane * 8]) = vb[i];
        }
        __syncthreads();
        tile_plain(As, Bs, wm, wn, lane, acc);
    }

    const int m15 = lane & 15, quad = lane >> 4;
#pragma unroll
    for (int i = 0; i < 4; ++i) {
#pragma unroll
        for (int t = 0; t < 4; ++t) {
            int row = row0 + wm * 64 + i * 16 + quad * 4 + t;
            size_t rb = (size_t)row * HID;
#pragma unroll
            for (int j = 0; j < 4; ++j) {
                int col = col0 + wn * 64 + j * 16 + m15;
                float v = acc[i][j][t] + b1[(size_t)e * HID + col];
                hid_[rb + col] = __float2bfloat16(fmaxf(v, 0.f));
            }
        }
    }
}

// ---------------------------------------------------------------------------
// Expert layer 2: exp_out[slot] = hid[slot] @ W2t[e]^T
// ---------------------------------------------------------------------------
__global__ __launch_bounds__(256)
void expert2_kernel(const __hip_bfloat16* hid_, const __hip_bfloat16* W2t_,
                    const int* __restrict__ offs, __hip_bfloat16* exp_out_)
{
    __shared__ __align__(16) short As[128 * 64];
    __shared__ __align__(16) short Bs[128 * 64];
    const short* A = (const short*)hid_;

    const int tid = threadIdx.x, lane = tid & 63, w = tid >> 6;
    const int wm = w & 1, wn = w >> 1;
    const int row0 = blockIdx.y * 128, col0 = blockIdx.x * 128;
    const int lr = lane >> 3, g = (lane & 7) ^ lr, colel = g * 8;

    int e = NEXP - 1;
    for (int q = 0; q < NEXP; ++q) { if (row0 < offs[q + 1]) { e = q; break; } }
    const short* B = (const short*)W2t_ + (size_t)e * D_OUT * HID;

    const short* pA[4];
    const short* pB[4];
#pragma unroll
    for (int i = 0; i < 4; ++i) {
        int r = w * 32 + i * 8 + lr;
        pA[i] = A + (size_t)(row0 + r) * HID + colel;
        pB[i] = B + (size_t)(col0 + r) * HID + colel;
    }

    floatx4 acc[4][4];
#pragma unroll
    for (int i = 0; i < 4; ++i)
#pragma unroll
        for (int j = 0; j < 4; ++j) acc[i][j] = (floatx4)(0.f);

    for (int k0 = 0; k0 < HID; k0 += 64) {
        bf16x8 va[4], vb[4];
#pragma unroll
        for (int i = 0; i < 4; ++i) {
            va[i] = *(const bf16x8*)(pA[i] + k0);
            vb[i] = *(const bf16x8*)(pB[i] + k0);
        }
        __syncthreads();
#pragma unroll
        for (int i = 0; i < 4; ++i) {
            *(bf16x8*)(&As[(w * 32 + i * 8) * 64 + lane * 8]) = va[i];
            *(bf16x8*)(&Bs[(w * 32 + i * 8) * 64 + lane * 8]) = vb[i];
        }
        __syncthreads();
        tile_plain(As, Bs, wm, wn, lane, acc);
    }

    const int m15 = lane & 15, quad = lane >> 4;
#pragma unroll
    for (int i = 0; i < 4; ++i) {
#pragma unroll
        for (int t = 0; t < 4; ++t) {
            int row = row0 + wm * 64 + i * 16 + quad * 4 + t;
            size_t rb = (size_t)row * D_OUT;
#pragma unroll
            for (int j = 0; j < 4; ++j) {
                int col = col0 + wn * 64 + j * 16 + m15;
                exp_out_[rb + col] = __float2bfloat16(acc[i][j][t]);
            }
        }
    }
}

// ---------------------------------------------------------------------------
// FUSED x-convert + gate: one pass over x (64 MB). Per token row:
//  - write x_hi/x_lo bf16 planes (coalesced short4 stores)
//  - accumulate 10 fp32 logits vs MgT[10][1024] staged in LDS (conflict-free
//    lane-contiguous b128 reads) -> shfl-reduce -> top-2 routing.
// Replaces the latency-bound 40B-strided Mg gather (R4: 390us, VALUBusy 2.4%).
// block = 4 waves x TPW tokens each; grid = N_TOK/(4*TPW).
// ---------------------------------------------------------------------------
#define TPW 8
__global__ __launch_bounds__(256)
void convert_gate_kernel(const float* __restrict__ x, const float* __restrict__ MgT,
                         const float* __restrict__ bgeff,
                         __hip_bfloat16* __restrict__ x_hi, __hip_bfloat16* __restrict__ x_lo,
                         int* __restrict__ route_e, float* __restrict__ route_w,
                         int* __restrict__ counts)
{
    __shared__ __align__(16) float mg[NEXP * 1024];   // 40 KB
    for (int i = threadIdx.x; i < NEXP * 256; i += 256)
        ((float4*)mg)[i] = ((const float4*)MgT)[i];
    __syncthreads();

    const int wave = threadIdx.x >> 6, lane = threadIdx.x & 63;
    const int tok0 = (blockIdx.x * 4 + wave) * TPW;

    for (int t = 0; t < TPW; ++t) {
        const int n = tok0 + t;
        const float* xrow = x + (size_t)n * D_IN;
        float p[NEXP];
#pragma unroll
        for (int e = 0; e < NEXP; ++e) p[e] = 0.f;

#pragma unroll
        for (int it = 0; it < 4; ++it) {
            const int d = it * 256 + lane * 4;
            float4 v = *(const float4*)(xrow + d);
            union { __hip_bfloat16 b[4]; short4 s; } uh, ul;
            uh.b[0] = __float2bfloat16(v.x); ul.b[0] = __float2bfloat16(v.x - __bfloat162float(uh.b[0]));
            uh.b[1] = __float2bfloat16(v.y); ul.b[1] = __float2bfloat16(v.y - __bfloat162float(uh.b[1]));
            uh.b[2] = __float2bfloat16(v.z); ul.b[2] = __float2bfloat16(v.z - __bfloat162float(uh.b[2]));
            uh.b[3] = __float2bfloat16(v.w); ul.b[3] = __float2bfloat16(v.w - __bfloat162float(uh.b[3]));
            *(short4*)(x_hi + (size_t)n * D_IN + d) = uh.s;
            *(short4*)(x_lo + (size_t)n * D_IN + d) = ul.s;
#pragma unroll
            for (int e = 0; e < NEXP; ++e) {
                const float4 m = *(const float4*)(&mg[e * 1024 + d]);
                p[e] += v.x * m.x + v.y * m.y + v.z * m.z + v.w * m.w;
            }
        }
#pragma unroll
        for (int e = 0; e < NEXP; ++e) {
            float v = p[e];
            for (int off = 32; off > 0; off >>= 1) v += __shfl_down(v, off);
            p[e] = v;
        }
        if (lane == 0) {
            float lg[NEXP];
#pragma unroll
            for (int e = 0; e < NEXP; ++e) lg[e] = p[e] + bgeff[e];
            int e0 = 0; float v0 = lg[0];
            for (int e = 1; e < NEXP; ++e) if (lg[e] > v0) { v0 = lg[e]; e0 = e; }
            int e1 = -1; float v1 = -3.0e38f;
            for (int e = 0; e < NEXP; ++e) {
                if (e == e0) continue;
                if (lg[e] > v1) { v1 = lg[e]; e1 = e; }
            }
            float w0 = 1.f / (1.f + expf(v1 - v0));   // softmax + top-2 renorm
            float w1 = 1.f - w0;
            route_e[n * 2]     = e0;
            route_e[n * 2 + 1] = e1;
            route_w[n * 2]     = w0;
            route_w[n * 2 + 1] = w1;
            atomicAdd(&counts[e0], 1);
            atomicAdd(&counts[e1], 1);
        }
    }
}

// ---------------------------------------------------------------------------
// fp32 [R][C] -> transposed bf16 [C][R] hi (+ optional lo); batched over z.
// ---------------------------------------------------------------------------
__global__ __launch_bounds__(256)
void transpose_cvt_kernel(const float* __restrict__ in, __hip_bfloat16* out_hi,
                          __hip_bfloat16* out_lo, int R, int C)
{
    __shared__ float t[32][33];
    const size_t zoff = (size_t)blockIdx.z * R * C;
    in += zoff; out_hi += zoff; if (out_lo) out_lo += zoff;
    const int c0 = blockIdx.x * 32, r0 = blockIdx.y * 32;
    const int tx = threadIdx.x & 31, ty = threadIdx.x >> 5;
#pragma unroll
    for (int i = 0; i < 4; ++i)
        t[ty + i * 8][tx] = in[(size_t)(r0 + ty + i * 8) * C + (c0 + tx)];
    __syncthreads();
#pragma unroll
    for (int i = 0; i < 4; ++i) {
        float v = t[tx][ty + i * 8];
        size_t o = (size_t)(c0 + ty + i * 8) * R + (r0 + tx);
        __hip_bfloat16 hi = __float2bfloat16(v);
        out_hi[o] = hi;
        if (out_lo) out_lo[o] = __float2bfloat16(v - __bfloat162float(hi));
    }
}

// ---------------------------------------------------------------------------
// Thin fp32 GEMM for gate-matrix chain: Cm = A[1024][1024] @ B[1024][10];
// trans=0 -> Cm[m][10]; trans=1 -> Cm[e][1024] (transposed write for MgT).
// ---------------------------------------------------------------------------
__global__ __launch_bounds__(256)
void wchain_kernel(const float* __restrict__ A, const float* __restrict__ B,
                   float* __restrict__ Cm, int trans)
{
    const int wave = threadIdx.x >> 6, lane = threadIdx.x & 63;
    const int m = blockIdx.x * 4 + wave;
    float acc[NEXP];
#pragma unroll
    for (int e = 0; e < NEXP; ++e) acc[e] = 0.f;
    const float* ar = A + (size_t)m * 1024;
    for (int d = lane; d < 1024; d += 64) {
        float av = ar[d];
        const float* br = B + (size_t)d * NEXP;
#pragma unroll
        for (int e = 0; e < NEXP; ++e) acc[e] += av * br[e];
    }
#pragma unroll
    for (int e = 0; e < NEXP; ++e) {
        float v = acc[e];
        for (int off = 32; off > 0; off >>= 1) v += __shfl_down(v, off);
        if (lane == 0) Cm[trans ? ((size_t)e * 1024 + m) : ((size_t)m * NEXP + e)] = v;
    }
}

// ---------------------------------------------------------------------------
// bg_eff = bg + bo@Wg + bv@t1 + bp@t2    (single block)
// ---------------------------------------------------------------------------
__global__ __launch_bounds__(256)
void bias_eff_kernel(const float* __restrict__ bp, const float* __restrict__ bv,
                     const float* __restrict__ bo, const float* __restrict__ bg,
                     const float* __restrict__ Wg, const float* __restrict__ t1,
                     const float* __restrict__ t2, float* __restrict__ bgeff)
{
    __shared__ float red[256];
    const int tid = threadIdx.x;
    float acc[NEXP];
#pragma unroll
    for (int e = 0; e < NEXP; ++e) acc[e] = 0.f;
    for (int d = tid; d < 1024; d += 256) {
        float o = bo[d], v = bv[d], p = bp[d];
#pragma unroll
        for (int e = 0; e < NEXP; ++e)
            acc[e] += o * Wg[d * NEXP + e] + v * t1[d * NEXP + e] + p * t2[d * NEXP + e];
    }
    for (int e = 0; e < NEXP; ++e) {
        red[tid] = acc[e];
        __syncthreads();
        for (int s = 128; s > 0; s >>= 1) {
            if (tid < s) red[tid] += red[tid + s];
            __syncthreads();
        }
        if (tid == 0) bgeff[e] = red[0] + bg[e];
        __syncthreads();
    }
}

// ---------------------------------------------------------------------------
__global__ __launch_bounds__(256)
void init_kernel(int* __restrict__ counts, int* __restrict__ cursors,
                 int* __restrict__ assign_token, int* __restrict__ zrow_i)
{
    int i = blockIdx.x * 256 + threadIdx.x;
    if (i < NEXP) { counts[i] = 0; cursors[i] = 0; }
    if (i < 512) zrow_i[i] = 0;                 // 1024 bf16 zeros
    if (i < A_CAP) assign_token[i] = -1;
}

__global__ void offsets_kernel(const int* __restrict__ counts, int* __restrict__ offs)
{
    if (threadIdx.x == 0 && blockIdx.x == 0) {
        int acc = 0;
        for (int e = 0; e < NEXP; ++e) {
            offs[e] = acc;
            acc += (counts[e] + EPAD - 1) / EPAD * EPAD;
        }
        offs[NEXP] = acc;
    }
}

__global__ __launch_bounds__(256)
void scatter_kernel(const int* __restrict__ route_e,
                    const int* __restrict__ offs, int* __restrict__ cursors,
                    int* __restrict__ assign_token, int* __restrict__ slot_of)
{
    int i = blockIdx.x * 256 + threadIdx.x;
    if (i >= 2 * N_TOK) return;
    int e = route_e[i];
    int slot = offs[e] + atomicAdd(&cursors[e], 1);
    assign_token[slot] = i >> 1;
    slot_of[i] = slot;
}

// ---------------------------------------------------------------------------
// Combine (gather): out[n] = w0*(row(s0)+b2[e0]) + w1*(row(s1)+b2[e1])
// ---------------------------------------------------------------------------
__global__ __launch_bounds__(256)
void combine_kernel(const __hip_bfloat16* __restrict__ exp_out,
                    const int* __restrict__ slot_of, const int* __restrict__ route_e,
                    const float* __restrict__ route_w, const float* __restrict__ b2,
                    float* __restrict__ out)
{
    const int n = blockIdx.x;
    const int c = threadIdx.x * 4;
    const int s0 = slot_of[n * 2],  s1 = slot_of[n * 2 + 1];
    const int e0 = route_e[n * 2],  e1 = route_e[n * 2 + 1];
    const float w0 = route_w[n * 2], w1 = route_w[n * 2 + 1];

    union U { float2 f2; __hip_bfloat16 b[4]; } u0, u1;
    u0.f2 = *(const float2*)(exp_out + (size_t)s0 * D_OUT + c);
    u1.f2 = *(const float2*)(exp_out + (size_t)s1 * D_OUT + c);
    const float4 bb0 = *(const float4*)(b2 + (size_t)e0 * D_OUT + c);
    const float4 bb1 = *(const float4*)(b2 + (size_t)e1 * D_OUT + c);

    float4 o;
    o.x = w0 * (__bfloat162float(u0.b[0]) + bb0.x) + w1 * (__bfloat162float(u1.b[0]) + bb1.x);
    o.y = w0 * (__bfloat162float(u0.b[1]) + bb0.y) + w1 * (__bfloat162float(u1.b[1]) + bb1.y);
    o.z = w0 * (__bfloat162float(u0.b[2]) + bb0.z) + w1 * (__bfloat162float(u1.b[2]) + bb1.z);
    o.w = w0 * (__bfloat162float(u0.b[3]) + bb0.w) + w1 * (__bfloat162float(u1.b[3]) + bb1.w);
    *(float4*)(out + (size_t)n * D_OUT + c) = o;
}

// ---------------------------------------------------------------------------
extern "C" void kernel_launch(void* const* d_in, const int* in_sizes, int n_in,
                              void* d_out, int out_size, void* d_ws, size_t ws_size,
                              hipStream_t stream)
{
    const float* x  = (const float*)d_in[0];
    const float* Wp = (const float*)d_in[2];
    const float* bp = (const float*)d_in[3];
    const float* Wv = (const float*)d_in[4];
    const float* bv = (const float*)d_in[5];
    const float* Wo = (const float*)d_in[6];
    const float* bo = (const float*)d_in[7];
    const float* Wg = (const float*)d_in[8];
    const float* bg = (const float*)d_in[9];
    const float* W1 = (const float*)d_in[10];
    const float* b1 = (const float*)d_in[11];
    const float* W2 = (const float*)d_in[12];
    const float* b2 = (const float*)d_in[13];
    float* out = (float*)d_out;

    // ---- workspace layout (bytes); lifetime-based aliasing, total ~150.6 MiB ----
    char* W = (char*)d_ws;
    typedef __hip_bfloat16 bf;
    bf* x_hi  = (bf*)(W + 0);                  // [N,D]  dead after gemm1
    bf* x_lo  = (bf*)(W + 33554432);           //        dead after gemm1
    bf* h_hi  = (bf*)(W + 67108864);           // dead after gemm2
    bf* h_lo  = (bf*)(W + 100663296);          // dead after gemm2
    bf* hv_hi = (bf*)(W + 0);                  // aliases x (dead) ; dead after gemm3
    bf* hv_lo = (bf*)(W + 33554432);
    bf* a_bf  = (bf*)(W + 100663296);          // aliases h_lo (dead); read by expert1
    bf* exp_out = (bf*)(W + 0);                // [A_CAP,D_OUT] 69.7MB; hv dead by then
    bf* hid   = (bf*)(W + 69730304);           // [A_CAP,HID] in dead h_hi region
    // weights (alive whole run)
    bf* Wpt_hi = (bf*)(W + 134217728);
    bf* Wpt_lo = (bf*)(W + 136314880);
    bf* Wvt_hi = (bf*)(W + 138412032);
    bf* Wvt_lo = (bf*)(W + 140509184);
    bf* Wot_hi = (bf*)(W + 142606336);
    bf* Wot_lo = (bf*)(W + 144703488);
    bf* W1t    = (bf*)(W + 146800640);         // [E][HID][D]
    bf* W2t    = (bf*)(W + 152043520);         // [E][D_OUT][HID]
    // small buffers
    bf*    zrow         = (bf*)(W + 157286400);       // 1024 bf16 zeros
    int*   route_e      = (int*)(W + 157288448);
    float* route_w      = (float*)(W + 157419520);
    int*   slot_of      = (int*)(W + 157550592);
    int*   assign_token = (int*)(W + 157681664);
    int*   counts       = (int*)(W + 157817856);
    int*   offs         = (int*)(W + 157817920);
    int*   cursors      = (int*)(W + 157817984);
    float* MgT          = (float*)(W + 157818048);    // [10][1024] transposed
    float* t1           = (float*)(W + 157859008);
    float* t2           = (float*)(W + 157899968);
    float* bgeff        = (float*)(W + 157940928);

    dim3 blk(256);

    // ---- weight conversions ----
    transpose_cvt_kernel<<<dim3(32, 32, 1), blk, 0, stream>>>(Wp, Wpt_hi, Wpt_lo, D_IN, D_MODEL);
    transpose_cvt_kernel<<<dim3(32, 32, 1), blk, 0, stream>>>(Wv, Wvt_hi, Wvt_lo, D_MODEL, D_MODEL);
    transpose_cvt_kernel<<<dim3(32, 32, 1), blk, 0, stream>>>(Wo, Wot_hi, Wot_lo, D_MODEL, D_MODEL);
    transpose_cvt_kernel<<<dim3(HID / 32, D_MODEL / 32, NEXP), blk, 0, stream>>>(W1, W1t, nullptr, D_MODEL, HID);
    transpose_cvt_kernel<<<dim3(D_OUT / 32, HID / 32, NEXP), blk, 0, stream>>>(W2, W2t, nullptr, HID, D_OUT);

    // ---- gate matrix chain (fp32, exactness-preserving associativity) ----
    wchain_kernel<<<256, blk, 0, stream>>>(Wo, Wg, t1, 0);   // t1 = Wo@Wg
    wchain_kernel<<<256, blk, 0, stream>>>(Wv, t1, t2, 0);   // t2 = Wv@t1
    wchain_kernel<<<256, blk, 0, stream>>>(Wp, t2, MgT, 1);  // MgT = (Wp@t2)^T
    bias_eff_kernel<<<1, blk, 0, stream>>>(bp, bv, bo, bg, Wg, t1, t2, bgeff);

    // ---- routing init + fused convert/gate ----
    init_kernel<<<(A_CAP + 255) / 256, blk, 0, stream>>>(counts, cursors, assign_token,
                                                         (int*)zrow);
    convert_gate_kernel<<<N_TOK / (4 * TPW), blk, 0, stream>>>(x, MgT, bgeff, x_hi, x_lo,
                                                               route_e, route_w, counts);
    offsets_kernel<<<1, 64, 0, stream>>>(counts, offs);
    scatter_kernel<<<(2 * N_TOK + 255) / 256, blk, 0, stream>>>(route_e, offs, cursors,
                                                                assign_token, slot_of);

    // ---- main chain: split-bf16 MFMA (~fp32 accuracy) ----
    dim3 cgrid(D_MODEL / 128, N_TOK / 128);   // (8, 128)
    gemm_split_kernel<<<cgrid, blk, 0, stream>>>(x_hi, x_lo, Wpt_hi, Wpt_lo, bp,
                                                 h_hi, h_lo, D_IN, D_MODEL);
    gemm_split_kernel<<<cgrid, blk, 0, stream>>>(h_hi, h_lo, Wvt_hi, Wvt_lo, bv,
                                                 hv_hi, hv_lo, D_MODEL, D_MODEL);
    gemm_split_kernel<<<cgrid, blk, 0, stream>>>(hv_hi, hv_lo, Wot_hi, Wot_lo, bo,
                                                 a_bf, nullptr, D_MODEL, D_MODEL);

    // ---- experts: plain bf16 MFMA, grouped by expert ----
    expert1_kernel<<<dim3(HID / 128, A_CAP / 128), blk, 0, stream>>>(
        a_bf, W1t, b1, assign_token, offs, zrow, hid);
    expert2_kernel<<<dim3(D_OUT / 128, A_CAP / 128), blk, 0, stream>>>(
        hid, W2t, offs, exp_out);
    combine_kernel<<<N_TOK, blk, 0, stream>>>(exp_out, slot_of, route_e, route_w, b2, out);
}